// Round 1
// baseline (115.191 us; speedup 1.0000x reference)
//
#include <hip/hip_runtime.h>
#include <math.h>

#define N_ORB   1024
#define NTIMES  1024
#define N_FZ    24
#define N_KEZ   6
#define N_TINT  64
#define N_ALPHA 512

// Workspace layout:
//   gT : [N_FZ][N_ALPHA][N_TINT] float   = 3,145,728 B   (grid slice, transposed)
//   P  : [NTIMES][N_ORB] float4          = 16,777,216 B  {dalpha, dMagEff, (s*64) as int bits, 0}
#define GT_BYTES (N_FZ * N_ALPHA * N_TINT * 4)

// ---------------------------------------------------------------------------
// Pass 0: gT[fz][s][tint] = grid[fz][kEZ_ind][tint][s]   (LDS-tiled transpose)
// grid dims: (24, 8) blocks of 256 threads; each block does a 64tint x 64s tile.
// ---------------------------------------------------------------------------
__global__ __launch_bounds__(256) void transpose_grid(
    const float* __restrict__ grid, const float* __restrict__ kEZs,
    const float* __restrict__ kEZ_val_p, float* __restrict__ gT)
{
    __shared__ float tile[64 * 65];   // +1 pad: conflict-free transposed reads

    // searchsorted(kEZs, kEZ_val, 'right') - 1  == (#elements <= val) - 1
    float kv = kEZ_val_p[0];
    int cnt = 0;
#pragma unroll
    for (int i = 0; i < N_KEZ; ++i) cnt += (kEZs[i] <= kv) ? 1 : 0;
    int kez = cnt - 1;
    kez = kez < 0 ? 0 : (kez > N_KEZ - 1 ? N_KEZ - 1 : kez);

    int fz   = blockIdx.x;          // 0..23
    int sc   = blockIdx.y;          // 0..7 (s-chunk of 64)
    int w    = threadIdx.x >> 6;
    int lane = threadIdx.x & 63;

    const float* gsrc = grid + ((size_t)fz * N_KEZ + kez) * N_TINT * N_ALPHA;

#pragma unroll
    for (int r = 0; r < 16; ++r) {
        int tint = w * 16 + r;
        tile[tint * 65 + lane] = gsrc[(size_t)tint * N_ALPHA + sc * 64 + lane];
    }
    __syncthreads();
#pragma unroll
    for (int r = 0; r < 16; ++r) {
        int sl = w * 16 + r;        // local s row
        gT[((size_t)fz * N_ALPHA + sc * 64 + sl) * N_TINT + lane] = tile[lane * 65 + sl];
    }
}

// ---------------------------------------------------------------------------
// Pass 1: P[t][o] = {dalpha, dMagEff, int_bits(s*64), 0}  (LDS-tiled transpose)
// grid dims: (16, 16) blocks of 256 threads; 64o x 64t tile per block.
// ---------------------------------------------------------------------------
__global__ __launch_bounds__(256) void prep_orbits(
    const float* __restrict__ alpha, const float* __restrict__ dMag,
    const float* __restrict__ alphas, float4* __restrict__ P)
{
    __shared__ float da_t[64 * 65];
    __shared__ float dm_t[64 * 65];
    __shared__ int   of_t[64 * 65];

    float al0 = alphas[0], al1 = alphas[N_ALPHA - 1];
    float la0 = log10f(al0);
    float inv_step = 1.0f / (log10f(alphas[1]) - la0);

    int o0 = blockIdx.y * 64, t0 = blockIdx.x * 64;
    int w = threadIdx.x >> 6, lane = threadIdx.x & 63;

#pragma unroll
    for (int r = 0; r < 16; ++r) {
        int ol = w * 16 + r;
        size_t idx = (size_t)(o0 + ol) * NTIMES + t0 + lane;
        float a = alpha[idx];
        float d = dMag[idx];
        float a_ind = (log10f(a) - la0) * inv_step;
        int a0i = (int)a_ind;                 // trunc toward zero == astype(int32)
        a0i = a0i < 0 ? 0 : (a0i > N_ALPHA - 1 ? N_ALPHA - 1 : a0i);
        float dal = a_ind - (float)a0i;       // vs clipped a0 (faithful)
        int s = a0i > N_ALPHA - 2 ? N_ALPHA - 2 : a0i;  // dynamic_slice clamp
        bool geom = (a >= al0) && (a <= al1);
        da_t[ol * 65 + lane] = dal;
        dm_t[ol * 65 + lane] = geom ? d : __builtin_inff();
        of_t[ol * 65 + lane] = s * N_TINT;    // float-word offset into gT slice
    }
    __syncthreads();
#pragma unroll
    for (int r = 0; r < 16; ++r) {
        int tl = w * 16 + r;
        float4 v;
        v.x = da_t[lane * 65 + tl];
        v.y = dm_t[lane * 65 + tl];
        v.z = __int_as_float(of_t[lane * 65 + tl]);
        v.w = 0.0f;
        P[(size_t)(t0 + tl) * N_ORB + o0 + lane] = v;   // coalesced 1KB store
    }
}

// ---------------------------------------------------------------------------
// Pass 2: one block per t (1024 blocks x 256 threads = 4 waves).
// Lane layout: q = lane>>4 selects one of 4 orbits/iter, (lane&15)*4 = tint quad.
// Per iteration: 1 broadcast float4 P-load + 2 float4 g-row loads -> 256 ops.
// ---------------------------------------------------------------------------
__global__ __launch_bounds__(256) void pdet_main(
    const float* __restrict__ fZ_vals, const float* __restrict__ fZs,
    const float* __restrict__ gT, const float4* __restrict__ P,
    float* __restrict__ out)
{
    __shared__ int red[4 * 64];

    int t = blockIdx.x;
    float lf0 = log10f(fZs[0]);
    float inv_f = 1.0f / (log10f(fZs[1]) - lf0);
    float fi = (log10f(fZ_vals[t]) - lf0) * inv_f;
    int f0 = (int)floorf(fi) + 1;
    f0 = f0 < 0 ? 0 : (f0 > N_FZ - 2 ? N_FZ - 2 : f0);

    const float*  gB = gT + (size_t)f0 * N_ALPHA * N_TINT;
    const float4* Pt = P + (size_t)t * N_ORB;

    int w = threadIdx.x >> 6, lane = threadIdx.x & 63;
    int q = lane >> 4;
    int tg = (lane & 15) << 2;      // tint quad start

    int c0 = 0, c1 = 0, c2 = 0, c3 = 0;
    int ob = w * 256 + q;

#pragma unroll 4
    for (int it = 0; it < 64; ++it) {
        float4 pd = Pt[ob + it * 4];
        float dal = pd.x, dm = pd.y;
        int offw = __float_as_int(pd.z);                 // s*64
        const float4* row = reinterpret_cast<const float4*>(gB + offw + tg);
        float4 g0 = row[0];
        float4 g1 = row[16];                             // +64 floats = row s+1
        c0 += dm < fmaf(dal, g1.x - g0.x, g0.x);
        c1 += dm < fmaf(dal, g1.y - g0.y, g0.y);
        c2 += dm < fmaf(dal, g1.z - g0.z, g0.z);
        c3 += dm < fmaf(dal, g1.w - g0.w, g0.w);
    }

    // sum over the 4 orbit-quads (lanes differing in bits 4,5)
    c0 += __shfl_xor(c0, 16); c0 += __shfl_xor(c0, 32);
    c1 += __shfl_xor(c1, 16); c1 += __shfl_xor(c1, 32);
    c2 += __shfl_xor(c2, 16); c2 += __shfl_xor(c2, 32);
    c3 += __shfl_xor(c3, 16); c3 += __shfl_xor(c3, 32);

    if (lane < 16) {
        red[w * 64 + lane * 4 + 0] = c0;
        red[w * 64 + lane * 4 + 1] = c1;
        red[w * 64 + lane * 4 + 2] = c2;
        red[w * 64 + lane * 4 + 3] = c3;
    }
    __syncthreads();
    if (threadIdx.x < 64) {
        int tot = red[threadIdx.x] + red[64 + threadIdx.x] +
                  red[128 + threadIdx.x] + red[192 + threadIdx.x];
        out[(size_t)t * N_TINT + threadIdx.x] = (float)tot * (1.0f / 1024.0f);
    }
}

// ---------------------------------------------------------------------------
extern "C" void kernel_launch(void* const* d_in, const int* in_sizes, int n_in,
                              void* d_out, int out_size, void* d_ws, size_t ws_size,
                              hipStream_t stream) {
    const float* alpha   = (const float*)d_in[0];
    const float* dMag    = (const float*)d_in[1];
    const float* fZ_vals = (const float*)d_in[2];
    const float* kEZ_val = (const float*)d_in[3];
    const float* grid    = (const float*)d_in[4];
    const float* fZs     = (const float*)d_in[5];
    const float* kEZs    = (const float*)d_in[6];
    const float* alphas  = (const float*)d_in[7];
    float*  out = (float*)d_out;

    float*  gT = (float*)d_ws;
    float4* P  = (float4*)((char*)d_ws + GT_BYTES);

    transpose_grid<<<dim3(N_FZ, N_ALPHA / 64), 256, 0, stream>>>(grid, kEZs, kEZ_val, gT);
    prep_orbits<<<dim3(NTIMES / 64, N_ORB / 64), 256, 0, stream>>>(alpha, dMag, alphas, P);
    pdet_main<<<dim3(NTIMES), 256, 0, stream>>>(fZ_vals, fZs, gT, P, out);
}

// Round 2
// 108.150 us; speedup vs baseline: 1.0651x; 1.0651x over previous
//
#include <hip/hip_runtime.h>
#include <math.h>

#define N_ORB   1024
#define NTIMES  1024
#define N_FZ    24
#define N_KEZ   6
#define N_TINT  64
#define N_ALPHA 512

// Workspace layout:
//   gT : [N_FZ][N_ALPHA][N_TINT] float   = 3,145,728 B   (grid slice, transposed)
//   P  : [NTIMES][N_ORB] float4          = 16,777,216 B  {dalpha, dMagEff, (s*64) as int bits, 0}
#define GT_BYTES (N_FZ * N_ALPHA * N_TINT * 4)

// ---------------------------------------------------------------------------
// Pass 0: gT[fz][s][tint] = grid[fz][kEZ_ind][tint][s]   (LDS-tiled transpose)
// ---------------------------------------------------------------------------
__global__ __launch_bounds__(256) void transpose_grid(
    const float* __restrict__ grid, const float* __restrict__ kEZs,
    const float* __restrict__ kEZ_val_p, float* __restrict__ gT)
{
    __shared__ float tile[64 * 65];

    float kv = kEZ_val_p[0];
    int cnt = 0;
#pragma unroll
    for (int i = 0; i < N_KEZ; ++i) cnt += (kEZs[i] <= kv) ? 1 : 0;
    int kez = cnt - 1;
    kez = kez < 0 ? 0 : (kez > N_KEZ - 1 ? N_KEZ - 1 : kez);

    int fz   = blockIdx.x;
    int sc   = blockIdx.y;
    int w    = threadIdx.x >> 6;
    int lane = threadIdx.x & 63;

    const float* gsrc = grid + ((size_t)fz * N_KEZ + kez) * N_TINT * N_ALPHA;

#pragma unroll
    for (int r = 0; r < 16; ++r) {
        int tint = w * 16 + r;
        tile[tint * 65 + lane] = gsrc[(size_t)tint * N_ALPHA + sc * 64 + lane];
    }
    __syncthreads();
#pragma unroll
    for (int r = 0; r < 16; ++r) {
        int sl = w * 16 + r;
        gT[((size_t)fz * N_ALPHA + sc * 64 + sl) * N_TINT + lane] = tile[lane * 65 + sl];
    }
}

// ---------------------------------------------------------------------------
// Pass 1: P[t][o] = {dalpha, dMagEff, int_bits(s*64), 0}  (LDS-tiled transpose)
// ---------------------------------------------------------------------------
__global__ __launch_bounds__(256) void prep_orbits(
    const float* __restrict__ alpha, const float* __restrict__ dMag,
    const float* __restrict__ alphas, float4* __restrict__ P)
{
    __shared__ float da_t[64 * 65];
    __shared__ float dm_t[64 * 65];
    __shared__ int   of_t[64 * 65];

    float al0 = alphas[0], al1 = alphas[N_ALPHA - 1];
    float la0 = log10f(al0);
    float inv_step = 1.0f / (log10f(alphas[1]) - la0);

    int o0 = blockIdx.y * 64, t0 = blockIdx.x * 64;
    int w = threadIdx.x >> 6, lane = threadIdx.x & 63;

#pragma unroll
    for (int r = 0; r < 16; ++r) {
        int ol = w * 16 + r;
        size_t idx = (size_t)(o0 + ol) * NTIMES + t0 + lane;
        float a = alpha[idx];
        float d = dMag[idx];
        float a_ind = (log10f(a) - la0) * inv_step;
        int a0i = (int)a_ind;                 // trunc toward zero == astype(int32)
        a0i = a0i < 0 ? 0 : (a0i > N_ALPHA - 1 ? N_ALPHA - 1 : a0i);
        float dal = a_ind - (float)a0i;
        int s = a0i > N_ALPHA - 2 ? N_ALPHA - 2 : a0i;  // dynamic_slice clamp
        bool geom = (a >= al0) && (a <= al1);
        da_t[ol * 65 + lane] = dal;
        dm_t[ol * 65 + lane] = geom ? d : __builtin_inff();
        of_t[ol * 65 + lane] = s * N_TINT;
    }
    __syncthreads();
#pragma unroll
    for (int r = 0; r < 16; ++r) {
        int tl = w * 16 + r;
        float4 v;
        v.x = da_t[lane * 65 + tl];
        v.y = dm_t[lane * 65 + tl];
        v.z = __int_as_float(of_t[lane * 65 + tl]);
        v.w = 0.0f;
        P[(size_t)(t0 + tl) * N_ORB + o0 + lane] = v;
    }
}

// ---------------------------------------------------------------------------
// Pass 2: one block per t. Phase A: counting-sort the 1024 orbits by s into
// LDS (bin 511 = geometry-masked dead orbits, truncated from the loop).
// Phase B: walk orbits in ascending-s order; 16 adjacent sorted orbits per
// iteration across the whole block -> g-rows advance monotonically, most
// group addresses per instr hit the same cache line.
// ---------------------------------------------------------------------------
__global__ __launch_bounds__(256) void pdet_main(
    const float* __restrict__ fZ_vals, const float* __restrict__ fZs,
    const float* __restrict__ gT, const float4* __restrict__ P,
    float* __restrict__ out)
{
    __shared__ float4 Psort[N_ORB];      // 16 KB sorted {dal, dm, offw, pad}
    __shared__ int    hist[512];
    __shared__ int    histPS[512];
    __shared__ int    red[4 * 64];
    __shared__ int    aliveLDS;

    int t = blockIdx.x;
    int tid = threadIdx.x;
    int w = tid >> 6, lane = tid & 63;

    float lf0 = log10f(fZs[0]);
    float inv_f = 1.0f / (log10f(fZs[1]) - lf0);
    float fi = (log10f(fZ_vals[t]) - lf0) * inv_f;
    int f0 = (int)floorf(fi) + 1;
    f0 = f0 < 0 ? 0 : (f0 > N_FZ - 2 ? N_FZ - 2 : f0);

    const float*  gB = gT + (size_t)f0 * N_ALPHA * N_TINT;
    const float4* Pt = P + (size_t)t * N_ORB;

    // ---- Phase A: load P row, histogram, scan, scatter ----
    hist[tid] = 0; hist[tid + 256] = 0;
    __syncthreads();

    float4 v[4];
    int    bin[4];
#pragma unroll
    for (int k = 0; k < 4; ++k) {
        v[k] = Pt[tid + k * 256];
        int s = __float_as_int(v[k].z) >> 6;           // offw / 64
        bin[k] = isinf(v[k].y) ? 511 : s;
        atomicAdd(&hist[bin[k]], 1);
    }
    __syncthreads();

    if (tid < 64) {   // wave 0: exclusive scan over 512 bins
        int pre[8]; int run = 0;
#pragma unroll
        for (int j = 0; j < 8; ++j) { pre[j] = run; run += hist[tid * 8 + j]; }
        int inc = run;
#pragma unroll
        for (int d = 1; d < 64; d <<= 1) {
            int n = __shfl_up(inc, d);
            if (lane >= d) inc += n;
        }
        int excl = inc - run;
#pragma unroll
        for (int j = 0; j < 8; ++j) histPS[tid * 8 + j] = excl + pre[j];
        if (tid == 63) aliveLDS = excl + pre[7] + hist[511] - hist[511]; // = start of bin 511
        if (tid == 63) aliveLDS = excl + pre[7];                         // exclusive start of bin 511
    }
    __syncthreads();

#pragma unroll
    for (int k = 0; k < 4; ++k) {
        int pos = atomicAdd(&histPS[bin[k]], 1);
        Psort[pos] = v[k];
    }
    __syncthreads();

    int alive = aliveLDS;
    int nIter = (alive + 15) >> 4;

    // ---- Phase B: main loop over sorted orbits ----
    int q  = lane >> 4;
    int tg = (lane & 15) << 2;
    int sid = w * 4 + q;                 // 0..15: adjacent sorted orbits per iter

    int c0 = 0, c1 = 0, c2 = 0, c3 = 0;

#pragma unroll 4
    for (int it = 0; it < nIter; ++it) {
        float4 pd = Psort[it * 16 + sid];
        float dal = pd.x, dm = pd.y;
        int offw = __float_as_int(pd.z);
        const float4* row = reinterpret_cast<const float4*>(gB + offw + tg);
        float4 g0 = row[0];
        float4 g1 = row[16];
        c0 += dm < fmaf(dal, g1.x - g0.x, g0.x);
        c1 += dm < fmaf(dal, g1.y - g0.y, g0.y);
        c2 += dm < fmaf(dal, g1.z - g0.z, g0.z);
        c3 += dm < fmaf(dal, g1.w - g0.w, g0.w);
    }

    c0 += __shfl_xor(c0, 16); c0 += __shfl_xor(c0, 32);
    c1 += __shfl_xor(c1, 16); c1 += __shfl_xor(c1, 32);
    c2 += __shfl_xor(c2, 16); c2 += __shfl_xor(c2, 32);
    c3 += __shfl_xor(c3, 16); c3 += __shfl_xor(c3, 32);

    if (lane < 16) {
        red[w * 64 + lane * 4 + 0] = c0;
        red[w * 64 + lane * 4 + 1] = c1;
        red[w * 64 + lane * 4 + 2] = c2;
        red[w * 64 + lane * 4 + 3] = c3;
    }
    __syncthreads();
    if (tid < 64) {
        int tot = red[tid] + red[64 + tid] + red[128 + tid] + red[192 + tid];
        out[(size_t)t * N_TINT + tid] = (float)tot * (1.0f / 1024.0f);
    }
}

// ---------------------------------------------------------------------------
extern "C" void kernel_launch(void* const* d_in, const int* in_sizes, int n_in,
                              void* d_out, int out_size, void* d_ws, size_t ws_size,
                              hipStream_t stream) {
    const float* alpha   = (const float*)d_in[0];
    const float* dMag    = (const float*)d_in[1];
    const float* fZ_vals = (const float*)d_in[2];
    const float* kEZ_val = (const float*)d_in[3];
    const float* grid    = (const float*)d_in[4];
    const float* fZs     = (const float*)d_in[5];
    const float* kEZs    = (const float*)d_in[6];
    const float* alphas  = (const float*)d_in[7];
    float*  out = (float*)d_out;

    float*  gT = (float*)d_ws;
    float4* P  = (float4*)((char*)d_ws + GT_BYTES);

    transpose_grid<<<dim3(N_FZ, N_ALPHA / 64), 256, 0, stream>>>(grid, kEZs, kEZ_val, gT);
    prep_orbits<<<dim3(NTIMES / 64, N_ORB / 64), 256, 0, stream>>>(alpha, dMag, alphas, P);
    pdet_main<<<dim3(NTIMES), 256, 0, stream>>>(fZ_vals, fZs, gT, P, out);
}

// Round 3
// 104.245 us; speedup vs baseline: 1.1050x; 1.0375x over previous
//
#include <hip/hip_runtime.h>
#include <math.h>

#define N_ORB   1024
#define NTIMES  1024
#define N_FZ    24
#define N_KEZ   6
#define N_TINT  64
#define N_ALPHA 512

// Workspace:
//   gT : [N_FZ][N_ALPHA][N_TINT] float  = 3,145,728 B  (grid slice, transposed)
//   P  : [NTIMES][N_ORB] float4         = 16,777,216 B {dalpha, dMagEff, int_bits(s*64), 0}
#define GT_BYTES (N_FZ * N_ALPHA * N_TINT * 4)

// ---------------------------------------------------------------------------
// Kernel 1: fused input staging. Blocks 0..191: gT transpose (64tint x 64s
// tile). Blocks 192..1215: P build, 32x32 (o,t) tiles -> ~4.75 blocks/CU.
// ---------------------------------------------------------------------------
__global__ __launch_bounds__(256) void stage_inputs(
    const float* __restrict__ grid, const float* __restrict__ kEZs,
    const float* __restrict__ kEZ_val_p, const float* __restrict__ alpha,
    const float* __restrict__ dMag, const float* __restrict__ alphas,
    float* __restrict__ gT, float4* __restrict__ P)
{
    __shared__ float lds[64 * 65];      // gT branch uses all; P branch aliases

    int b = blockIdx.x;
    if (b < 192) {
        // ---- gT[fz][s][tint] = grid[fz][kez][tint][s] ----
        float kv = kEZ_val_p[0];
        int cnt = 0;
#pragma unroll
        for (int i = 0; i < N_KEZ; ++i) cnt += (kEZs[i] <= kv) ? 1 : 0;
        int kez = cnt - 1;
        kez = kez < 0 ? 0 : (kez > N_KEZ - 1 ? N_KEZ - 1 : kez);

        int fz = b >> 3, sc = b & 7;
        int w = threadIdx.x >> 6, lane = threadIdx.x & 63;
        const float* gsrc = grid + ((size_t)fz * N_KEZ + kez) * N_TINT * N_ALPHA;

#pragma unroll
        for (int r = 0; r < 16; ++r) {
            int tint = w * 16 + r;
            lds[tint * 65 + lane] = gsrc[(size_t)tint * N_ALPHA + sc * 64 + lane];
        }
        __syncthreads();
#pragma unroll
        for (int r = 0; r < 16; ++r) {
            int sl = w * 16 + r;
            gT[((size_t)fz * N_ALPHA + sc * 64 + sl) * N_TINT + lane] = lds[lane * 65 + sl];
        }
    } else {
        // ---- P[t][o] = {dal, dMagEff, int_bits(s*64), 0}, 32x32 tile ----
        float* da = lds;                 // [32][33]
        float* dm = lds + 1056;
        int*   of = (int*)(lds + 2112);

        int u = b - 192;                 // 0..1023
        int t0 = (u & 31) * 32, o0 = (u >> 5) * 32;
        int row = threadIdx.x >> 5, col = threadIdx.x & 31;

        float al0 = alphas[0], al1 = alphas[N_ALPHA - 1];
        float la0 = log10f(al0);
        float inv_step = 1.0f / (log10f(alphas[1]) - la0);

#pragma unroll
        for (int r = 0; r < 4; ++r) {
            int ol = r * 8 + row;
            size_t idx = (size_t)(o0 + ol) * NTIMES + t0 + col;
            float a = alpha[idx];
            float d = dMag[idx];
            float a_ind = (log10f(a) - la0) * inv_step;
            int a0i = (int)a_ind;                    // trunc == astype(int32)
            a0i = a0i < 0 ? 0 : (a0i > N_ALPHA - 1 ? N_ALPHA - 1 : a0i);
            float dal = a_ind - (float)a0i;
            int s = a0i > N_ALPHA - 2 ? N_ALPHA - 2 : a0i;   // dynamic_slice clamp
            bool geom = (a >= al0) && (a <= al1);
            da[ol * 33 + col] = dal;
            dm[ol * 33 + col] = geom ? d : __builtin_inff();
            of[ol * 33 + col] = s * N_TINT;
        }
        __syncthreads();
#pragma unroll
        for (int r = 0; r < 4; ++r) {
            int tl = r * 8 + row;
            float4 v;
            v.x = da[col * 33 + tl];
            v.y = dm[col * 33 + tl];
            v.z = __int_as_float(of[col * 33 + tl]);
            v.w = 0.0f;
            P[(size_t)(t0 + tl) * N_ORB + o0 + col] = v;
        }
    }
}

// ---------------------------------------------------------------------------
// Kernel 2: one block per t.
// Phase A: counting-sort orbits by s into LDS (dead orbits -> bin 511 tail).
// Phase B: wave w owns sorted range [w*256, w*256+256), 4 ADJACENT sorted
// orbits per iteration (one per 16-lane group) -> g-loads mostly hit the
// same/adjacent rows (few distinct lines per instr), rows advance
// monotonically within each wave's quarter-range (L1-resident).
// ---------------------------------------------------------------------------
__global__ __launch_bounds__(256) void pdet_main(
    const float* __restrict__ fZ_vals, const float* __restrict__ fZs,
    const float* __restrict__ gT, const float4* __restrict__ P,
    float* __restrict__ out)
{
    __shared__ float4 Psort[N_ORB];      // 16 KB
    __shared__ int    hist[512];
    __shared__ int    histPS[512];
    __shared__ int    red[4 * 64];

    int t = blockIdx.x;
    int tid = threadIdx.x;
    int w = tid >> 6, lane = tid & 63;

    float lf0 = log10f(fZs[0]);
    float inv_f = 1.0f / (log10f(fZs[1]) - lf0);
    float fi = (log10f(fZ_vals[t]) - lf0) * inv_f;
    int f0 = (int)floorf(fi) + 1;
    f0 = f0 < 0 ? 0 : (f0 > N_FZ - 2 ? N_FZ - 2 : f0);

    const float*  gB = gT + (size_t)f0 * N_ALPHA * N_TINT;
    const float4* Pt = P + (size_t)t * N_ORB;

    // ---- Phase A ----
    hist[tid] = 0; hist[tid + 256] = 0;
    __syncthreads();

    float4 v[4];
    int    bin[4];
#pragma unroll
    for (int k = 0; k < 4; ++k) {
        v[k] = Pt[tid + k * 256];
        int s = __float_as_int(v[k].z) >> 6;
        bin[k] = isinf(v[k].y) ? 511 : s;
        atomicAdd(&hist[bin[k]], 1);
    }
    __syncthreads();

    if (tid < 64) {                      // wave 0: exclusive scan of 512 bins
        int pre[8]; int run = 0;
#pragma unroll
        for (int j = 0; j < 8; ++j) { pre[j] = run; run += hist[tid * 8 + j]; }
        int inc = run;
#pragma unroll
        for (int d = 1; d < 64; d <<= 1) {
            int n = __shfl_up(inc, d);
            if (lane >= d) inc += n;
        }
        int excl = inc - run;
#pragma unroll
        for (int j = 0; j < 8; ++j) histPS[tid * 8 + j] = excl + pre[j];
    }
    __syncthreads();

#pragma unroll
    for (int k = 0; k < 4; ++k) {
        int pos = atomicAdd(&histPS[bin[k]], 1);
        Psort[pos] = v[k];
    }
    __syncthreads();

    // ---- Phase B ----
    int q  = lane >> 4;                  // group 0..3 -> adjacent sorted orbit
    int tg = (lane & 15) << 2;           // tint quad
    int base = w * 256;                  // this wave's sorted range

    int c0 = 0, c1 = 0, c2 = 0, c3 = 0;

#pragma unroll 4
    for (int it = 0; it < 64; ++it) {
        float4 pd = Psort[base + it * 4 + q];
        float dal = pd.x, dm = pd.y;
        int offw = __float_as_int(pd.z);
        const float4* rowp = reinterpret_cast<const float4*>(gB + offw + tg);
        float4 g0 = rowp[0];
        float4 g1 = rowp[16];            // row s+1
        c0 += dm < fmaf(dal, g1.x - g0.x, g0.x);
        c1 += dm < fmaf(dal, g1.y - g0.y, g0.y);
        c2 += dm < fmaf(dal, g1.z - g0.z, g0.z);
        c3 += dm < fmaf(dal, g1.w - g0.w, g0.w);
    }

    c0 += __shfl_xor(c0, 16); c0 += __shfl_xor(c0, 32);
    c1 += __shfl_xor(c1, 16); c1 += __shfl_xor(c1, 32);
    c2 += __shfl_xor(c2, 16); c2 += __shfl_xor(c2, 32);
    c3 += __shfl_xor(c3, 16); c3 += __shfl_xor(c3, 32);

    if (lane < 16) {
        red[w * 64 + lane * 4 + 0] = c0;
        red[w * 64 + lane * 4 + 1] = c1;
        red[w * 64 + lane * 4 + 2] = c2;
        red[w * 64 + lane * 4 + 3] = c3;
    }
    __syncthreads();
    if (tid < 64) {
        int tot = red[tid] + red[64 + tid] + red[128 + tid] + red[192 + tid];
        out[(size_t)t * N_TINT + tid] = (float)tot * (1.0f / 1024.0f);
    }
}

// ---------------------------------------------------------------------------
extern "C" void kernel_launch(void* const* d_in, const int* in_sizes, int n_in,
                              void* d_out, int out_size, void* d_ws, size_t ws_size,
                              hipStream_t stream) {
    const float* alpha   = (const float*)d_in[0];
    const float* dMag    = (const float*)d_in[1];
    const float* fZ_vals = (const float*)d_in[2];
    const float* kEZ_val = (const float*)d_in[3];
    const float* grid    = (const float*)d_in[4];
    const float* fZs     = (const float*)d_in[5];
    const float* kEZs    = (const float*)d_in[6];
    const float* alphas  = (const float*)d_in[7];
    float*  out = (float*)d_out;

    float*  gT = (float*)d_ws;
    float4* P  = (float4*)((char*)d_ws + GT_BYTES);

    stage_inputs<<<dim3(192 + 1024), 256, 0, stream>>>(
        grid, kEZs, kEZ_val, alpha, dMag, alphas, gT, P);
    pdet_main<<<dim3(NTIMES), 256, 0, stream>>>(fZ_vals, fZs, gT, P, out);
}